// Round 6
// baseline (718.064 us; speedup 1.0000x reference)
//
#include <hip/hip_runtime.h>
#include <hip/hip_cooperative_groups.h>

namespace cg = cooperative_groups;

#define N_NODES  200000
#define N_CHILD  32
#define N_LAYERS 8
#define CHUNK    40000   // bf16 per window; 2 windows * 80000 B = 160000 B LDS (max 163840)
#define NCHUNK   5       // 5 * 40000 = 200000 exactly
#define NB       256     // 1 block per CU (co-resident: cooperative launch)
#define NPB      782     // ceil(200000/256) nodes per block
#define BT       832     // 13 waves
#define NWAVE    (BT / 64)            // 13
#define W16      (CHUNK / 8)          // 16B units per window = 5000
#define NSEG     ((W16 + 63) / 64)    // 79 wave-segments

#define AS1 __attribute__((address_space(1)))
#define AS3 __attribute__((address_space(3)))

// v9: fused cooperative kernel. R5 post-mortem: marginal staged-byte rate is
// ~20 B/cyc/CU (fast) but a ~38us/layer FIXED cost persists across all
// variations -> the serial per-launch prologue: 100 KB/CU of child_idx
// gathered from cold HBM (the 800MB workspace poison flushes IC every
// iteration) at MSHR-limited latency, un-overlappable because registers die
// at kernel boundaries. Fuse all 8 layers (grid.sync between), keep the
// VERIFIED R5 window/probe structure, and prefetch layer l+1's child_idx
// (2 x int4 per window, unpack after probes) during layer l's window loop.
// Also folds the X->bf16 cvt in and drops 7 launch overheads.
__device__ __forceinline__ void stage_window_async(const ushort* __restrict__ src,
                                                   ushort* dst, int wave, int lane)
{
    #pragma unroll
    for (int sg = 0; sg < (NSEG + NWAVE - 1) / NWAVE; ++sg) {
        const int seg = wave + sg * NWAVE;
        const int e   = (seg << 6) + lane;          // 16B-unit index within window
        if (seg < NSEG && e < W16) {
            __builtin_amdgcn_global_load_lds(
                (const AS1 void*)(const void*)(src + (size_t)e * 8),
                (AS3 void*)(void*)(dst + (size_t)e * 8),
                16, 0, 0);
        }
    }
}

__device__ __forceinline__ ushort f32_to_bf16_rne(float x) {
    unsigned u = __builtin_bit_cast(unsigned, x);
    u += 0x7FFFu + ((u >> 16) & 1u);
    return (ushort)(u >> 16);
}

__global__ __launch_bounds__(BT) void fused_kernel(
    const float* __restrict__ X,
    float*       __restrict__ out_f32,
    ushort*      __restrict__ bufA,
    ushort*      __restrict__ bufB,
    const int*   __restrict__ child_idx,   // [N_LAYERS][N_NODES][N_CHILD]
    const int*   __restrict__ fun_ids,     // [N_LAYERS][N_NODES]
    const float* __restrict__ wptr)
{
    cg::grid_group grid = cg::this_grid();
    __shared__ __align__(16) ushort lds[2][CHUNK];
    const int tid    = threadIdx.x;
    const int wave   = tid >> 6;
    const int lane   = tid & 63;
    const int node   = blockIdx.x * NPB + tid;
    const bool active = (tid < NPB) && (node < N_NODES);
    const float w0   = wptr[0];

    // ---- folded cvt: X (f32) -> bufA (bf16) ----
    const int gtid = blockIdx.x * BT + tid;          // 212992 threads >= 50000 float4
    if (gtid < N_NODES / 4) {
        float4 v = ((const float4*)X)[gtid];
        ushort4 r;
        r.x = f32_to_bf16_rne(v.x); r.y = f32_to_bf16_rne(v.y);
        r.z = f32_to_bf16_rne(v.z); r.w = f32_to_bf16_rne(v.w);
        ((ushort4*)bufA)[gtid] = r;
    }

    // layer-0 children -> registers (the one cold, serial prologue)
    int idxA[N_CHILD], idxB[N_CHILD];
    int fidA = 3, fidB = 3;
    if (active) {
        const int4* ci = (const int4*)(child_idx + (size_t)node * N_CHILD);
        #pragma unroll
        for (int j = 0; j < N_CHILD / 4; ++j) {
            int4 c = ci[j];
            idxA[4*j+0] = c.x; idxA[4*j+1] = c.y;
            idxA[4*j+2] = c.z; idxA[4*j+3] = c.w;
        }
        fidA = fun_ids[node];
    } else {
        #pragma unroll
        for (int j = 0; j < N_CHILD; ++j) idxA[j] = 0;
    }
    #pragma unroll
    for (int j = 0; j < N_CHILD; ++j) idxB[j] = 0;

    grid.sync();   // cvt results visible grid-wide

    auto layer_body = [&](int l, int (&idxC)[N_CHILD], int fidC,
                          int (&idxN)[N_CHILD], int& fidN) {
        const ushort* __restrict__ cur = (l & 1) ? bufB : bufA;
        stage_window_async(cur, lds[0], wave, lane);
        __syncthreads();   // window 0 staged (vmcnt0 drain)

        const size_t nlbase = (size_t)((l + 1 < N_LAYERS) ? l + 1 : l) * N_NODES;
        const int4* cin = (const int4*)(child_idx + nlbase * N_CHILD + (size_t)node * N_CHILD);

        float s = 0.0f;
        #pragma unroll 1
        for (int c = 0; c < NCHUNK; ++c) {
            if (c + 1 < NCHUNK)
                stage_window_async(cur + (size_t)(c + 1) * CHUNK,
                                   lds[(c + 1) & 1], wave, lane);

            // issue next-layer child prefetch EARLY (2 int4 per window, c=0..3);
            // unpack AFTER probes so the vmcnt-wait overlaps the probe phase
            int4 pa, pb;
            const bool pf = (l + 1 < N_LAYERS) && (c < 4) && active;
            if (pf) {
                pa = cin[2 * c];
                pb = cin[2 * c + 1];
                if (c == 0) fidN = fun_ids[nlbase + node];
            }

            const ushort* __restrict__ buf = lds[c & 1];
            const unsigned cbase = (unsigned)(c * CHUNK);
            #pragma unroll
            for (int j = 0; j < N_CHILD; ++j) {
                unsigned off = (unsigned)idxC[j] - cbase;
                bool in   = off < (unsigned)CHUNK;
                ushort rw = buf[in ? off : 0u];                       // in-bounds, no branch
                float v   = __builtin_bit_cast(float, (unsigned)rw << 16);
                s += in ? v : 0.0f;                                   // cndmask, no branch
            }

            if (pf) {
                idxN[8*c+0] = pa.x; idxN[8*c+1] = pa.y; idxN[8*c+2] = pa.z; idxN[8*c+3] = pa.w;
                idxN[8*c+4] = pb.x; idxN[8*c+5] = pb.y; idxN[8*c+6] = pb.z; idxN[8*c+7] = pb.w;
            }
            __syncthreads();   // probes done + stage(c+1) complete
        }

        if (active) {
            float x = w0 * s;
            float y;
            if (fidC == 0)      y = tanhf(x);
            else if (fidC == 1) y = 1.0f / (1.0f + __expf(-x));  // safe at +-inf
            else if (fidC == 2) y = fmaxf(x, 0.0f);
            else                y = x;
            if (l == N_LAYERS - 1) out_f32[node] = y;
            else {
                ushort* nxt = (l & 1) ? bufA : bufB;
                nxt[node] = f32_to_bf16_rne(y);
            }
        }
        if (l + 1 < N_LAYERS) grid.sync();   // layer outputs visible grid-wide
    };

    #pragma unroll 1
    for (int lp = 0; lp < N_LAYERS / 2; ++lp) {
        layer_body(2 * lp,     idxA, fidA, idxB, fidB);
        layer_body(2 * lp + 1, idxB, fidB, idxA, fidA);
    }
}

extern "C" void kernel_launch(void* const* d_in, const int* in_sizes, int n_in,
                              void* d_out, int out_size, void* d_ws, size_t ws_size,
                              hipStream_t stream) {
    const float* X         = (const float*)d_in[0];
    const float* w         = (const float*)d_in[1];
    const int*   child_idx = (const int*)d_in[2];
    const int*   fun_ids   = (const int*)d_in[3];
    float*       out       = (float*)d_out;
    ushort*      bufA      = (ushort*)d_ws;                      // 400 KB bf16 ping
    ushort*      bufB      = (ushort*)((char*)d_ws + 512000);    // 400 KB bf16 pong

    void* args[] = { (void*)&X, (void*)&out, (void*)&bufA, (void*)&bufB,
                     (void*)&child_idx, (void*)&fun_ids, (void*)&w };
    hipLaunchCooperativeKernel((void*)fused_kernel, dim3(NB), dim3(BT),
                               args, 0, stream);
}